// Round 6
// baseline (326.795 us; speedup 1.0000x reference)
//
#include <hip/hip_runtime.h>
#include <hip/hip_cooperative_groups.h>

namespace cg = cooperative_groups;

// B=16, C=3, H=256, W=256 fp32. 48 slices of 256x256.
// out = inverted, per-slice max-normalized, per-channel-weighted exact EDT.
//
// SINGLE cooperative kernel, 768 blocks x 256 threads (co-residency validated
// by hipLaunchCooperativeKernel; LDS 18.5KB -> 8 blk/CU, VGPR<=128 -> 4 blk/CU).
//   Phase 1: block bx computes g (1D nearest-zero distance) for rows
//            bx*16..bx*16+15 entirely in ballot registers, writes u16 g.
//   Phase 2: block bx = strip (slice bx>>4, cols (bx&15)*16..+15): g strip ->
//            LDS (d^2 float, col-major stride 289, 16 pad rows each side);
//            own[16] contiguous rows in regs; +-16 paired window min-plus;
//            EXACT fallback (full-column rescan in LDS) when windowed
//            min > 288 (|o|>=17 candidates >= 289). dmin stays in REGISTERS.
//            Block max -> atomicMax(ctrl[slice]) (float-as-uint, d2>=0).
//   Phase 3: after grid.sync, read slice max, write final
//            out = (mx - w*sqrt(d2))/mx straight from registers.
// d2 never touches HBM; k3's 25 MB round trip and 2 launch gaps are gone.

#define PADV 1e30f

__global__ __launch_bounds__(256) __attribute__((amdgpu_waves_per_eu(4)))
void kfused(const float* __restrict__ in, float* __restrict__ out,
            unsigned short* __restrict__ g, unsigned* __restrict__ ctrl) {
    __shared__ float tile[16 * 289];   // 18496 B
    __shared__ float wm[4];
    __shared__ float sMx;
    cg::grid_group grid = cg::this_grid();

    int bx = blockIdx.x;               // 0..767
    int tid = threadIdx.x;
    int lane = tid & 63;
    int wv = tid >> 6;                 // wave 0..3

    if (bx == 0 && tid < 64) ctrl[tid] = 0u;   // slice maxes (48 used)

    // ---------------- phase 1: g16 via ballots, 4 rows per wave -------------
    // Lane l holds cols 4l..4l+3. b[cc] bit j = (col 4j+cc == 0).
    {
        unsigned long long loP = ~0ull >> (63 - lane);  // bits 0..lane
        unsigned long long loM = loP >> 1;              // bits 0..lane-1
        unsigned long long hiP = ~0ull << lane;         // bits lane..63
        unsigned long long hiM = hiP << 1;              // bits lane+1..63
        #pragma unroll
        for (int i = 0; i < 4; ++i) {
            int row = bx * 16 + wv * 4 + i;             // rows 0..12287
            const float4 m = ((const float4*)in)[(long)row * 64 + lane];
            unsigned long long b[4];
            b[0] = __ballot(m.x == 0.f);
            b[1] = __ballot(m.y == 0.f);
            b[2] = __ballot(m.z == 0.f);
            b[3] = __ballot(m.w == 0.f);

            int LP[4], LM[4], RP[4], RM[4];
            #pragma unroll
            for (int cc = 0; cc < 4; ++cc) {
                unsigned long long mlp = b[cc] & loP;
                unsigned long long mlm = b[cc] & loM;
                unsigned long long mhp = b[cc] & hiP;
                unsigned long long mhm = b[cc] & hiM;
                LP[cc] = mlp ? 4 * (63 - __builtin_clzll(mlp)) + cc : -1000;
                LM[cc] = mlm ? 4 * (63 - __builtin_clzll(mlm)) + cc : -1000;
                RP[cc] = mhp ? 4 * __builtin_ctzll(mhp) + cc : 2000;
                RM[cc] = mhm ? 4 * __builtin_ctzll(mhm) + cc : 2000;
            }
            // colL(ci) = max( LP[cc] for cc<=ci, LM[cc] for cc>ci )
            int qp1 = max(LP[0], LP[1]);
            int qp2 = max(qp1, LP[2]);
            int qp3 = max(qp2, LP[3]);
            int sm3 = LM[3];
            int sm2 = max(LM[2], sm3);
            int sm1 = max(LM[1], sm2);
            int colL0 = max(LP[0], sm1);
            int colL1 = max(qp1, sm2);
            int colL2 = max(qp2, sm3);
            int colL3 = qp3;
            // colR(ci) = min( RM[cc] for cc<ci, RP[cc] for cc>=ci )
            int sp2 = min(RP[2], RP[3]);
            int sp1 = min(RP[1], sp2);
            int sp0 = min(RP[0], sp1);
            int pm0 = RM[0];
            int pm1 = min(pm0, RM[1]);
            int pm2 = min(pm1, RM[2]);
            int colR0 = sp0;
            int colR1 = min(pm0, sp1);
            int colR2 = min(pm1, sp2);
            int colR3 = min(pm2, RP[3]);

            int p0 = lane * 4;
            int d0 = min(min(p0 - colL0, colR0 - p0), 512);        // cap = BIG
            int d1 = min(min(p0 + 1 - colL1, colR1 - p0 - 1), 512);
            int d2 = min(min(p0 + 2 - colL2, colR2 - p0 - 2), 512);
            int d3 = min(min(p0 + 3 - colL3, colR3 - p0 - 3), 512);

            ushort4 v;
            v.x = (unsigned short)d0; v.y = (unsigned short)d1;
            v.z = (unsigned short)d2; v.w = (unsigned short)d3;
            ((ushort4*)(g + (long)row * 256))[lane] = v;           // coalesced
        }
    }
    __threadfence();
    grid.sync();

    // ---------------- phase 2: column min-plus for strip bx -----------------
    int slice = bx >> 4;
    int w0 = (bx & 15) * 16;

    // fill tile: idx 0..287 <-> row idx-16; thread tid does idx=tid, tid<32 also idx=256+tid
    #pragma unroll
    for (int pass = 0; pass < 2; ++pass) {
        int idx = pass * 256 + tid;
        if (pass == 0 || tid < 32) {
            int r = idx - 16;
            if (r >= 0 && r < 256) {
                const uint4* src = (const uint4*)(g + (long)slice * 65536 + (long)r * 256 + w0);
                #pragma unroll
                for (int j = 0; j < 2; ++j) {
                    uint4 q = src[j];
                    unsigned vv[4] = {q.x, q.y, q.z, q.w};
                    #pragma unroll
                    for (int e = 0; e < 4; ++e) {
                        float dl = (float)(vv[e] & 0xffffu);
                        float dh = (float)(vv[e] >> 16);
                        int col = j * 8 + e * 2;
                        tile[col * 289 + idx] = dl * dl;
                        tile[(col + 1) * 289 + idx] = dh * dh;
                    }
                }
            } else {
                #pragma unroll
                for (int cc = 0; cc < 16; ++cc) tile[cc * 289 + idx] = PADV;
            }
        }
    }
    __syncthreads();

    int c = tid & 15;                  // column within strip
    int rg = tid >> 4;                 // 0..15
    int r0 = rg * 16;                  // owned rows r0..r0+15
    int i0 = 16 + r0;                  // tile index of first owned row

    float own[16], lo[16], hi[16];
    #pragma unroll
    for (int k = 0; k < 16; ++k) own[k] = tile[c * 289 + i0 + k];
    #pragma unroll
    for (int i = 0; i < 16; ++i) {
        lo[i] = tile[c * 289 + i0 - 16 + i];   // rows r0-16..r0-1 (pads rg==0)
        hi[i] = tile[c * 289 + i0 + 16 + i];   // rows r0+16..r0+31 (pads rg==15)
    }

    // window min-plus, +-o paired: min(s[k-o], s[k+o]) + o^2
    float dmin[16];
    #pragma unroll
    for (int k = 0; k < 16; ++k) dmin[k] = own[k];
    #pragma unroll
    for (int o = 1; o <= 16; ++o) {
        float oo = (float)(o * o);
        #pragma unroll
        for (int k = 0; k < 16; ++k) {
            int jm = k - o, jp = k + o;
            float a = (jm >= 0) ? own[jm] : lo[jm + 16];
            float b = (jp < 16) ? own[jp] : hi[jp - 16];
            dmin[k] = fminf(dmin[k], fminf(a, b) + oo);
        }
    }

    // exact fallback: windowed min > 288 can't certify +-16 optimality;
    // rescan the full column (in LDS). Never taken for random masks (execz).
    #pragma unroll
    for (int k = 0; k < 16; ++k) {
        if (dmin[k] > 288.0f) {
            float best = dmin[k];
            int r = r0 + k;
            for (int rp = 0; rp < 256; ++rp) {
                float dr = (float)(r - rp);
                best = fminf(best, fmaf(dr, dr, tile[c * 289 + 16 + rp]));
            }
            dmin[k] = best;
        }
    }

    // block max -> slice max (float-as-uint atomicMax, valid: d2 >= 0)
    float mmax = 0.f;
    #pragma unroll
    for (int k = 0; k < 16; ++k) mmax = fmaxf(mmax, dmin[k]);
    #pragma unroll
    for (int off = 32; off >= 1; off >>= 1)
        mmax = fmaxf(mmax, __shfl_down(mmax, off, 64));
    if ((tid & 63) == 0) wm[tid >> 6] = mmax;
    __syncthreads();
    if (tid == 0)
        atomicMax(ctrl + slice,
                  __float_as_uint(fmaxf(fmaxf(wm[0], wm[1]), fmaxf(wm[2], wm[3]))));
    __threadfence();
    grid.sync();

    // ---------------- phase 3: epilogue straight from registers -------------
    if (tid == 0)
        sMx = __uint_as_float(ctrl[slice]);
    __syncthreads();

    int ch = slice % 3;
    float wgt = (ch == 0) ? 0.5f : ((ch == 1) ? 1.0f : 2.0f);
    float mx = wgt * __builtin_sqrtf(sMx);
    float* dst = out + (long)slice * 65536 + w0 + c;
    if (mx > 0.f) {
        float inv = 1.0f / mx;
        #pragma unroll
        for (int k = 0; k < 16; ++k)
            dst[(long)(r0 + k) * 256] = (mx - wgt * __builtin_sqrtf(dmin[k])) * inv;
    } else {
        #pragma unroll
        for (int k = 0; k < 16; ++k)
            dst[(long)(r0 + k) * 256] = wgt * __builtin_sqrtf(dmin[k]);
    }
}

extern "C" void kernel_launch(void* const* d_in, const int* in_sizes, int n_in,
                              void* d_out, int out_size, void* d_ws, size_t ws_size,
                              hipStream_t stream) {
    const float* in = (const float*)d_in[0];
    float* out = (float*)d_out;
    unsigned* ctrl = (unsigned*)d_ws;                                  // 64 uints
    unsigned short* g = (unsigned short*)((char*)d_ws + 4096);         // 6.29 MB

    void* args[] = { (void*)&in, (void*)&out, (void*)&g, (void*)&ctrl };
    hipLaunchCooperativeKernel((void*)kfused, dim3(768), dim3(256),
                               args, 0, stream);
}

// Round 7
// 120.804 us; speedup vs baseline: 2.7052x; 2.7052x over previous
//
#include <hip/hip_runtime.h>

// B=16, C=3, H=256, W=256 fp32. 48 slices of 256x256.
// out = inverted, per-slice max-normalized, per-channel-weighted exact EDT.
//
// Pipeline (2 launches, fused epilogue via device-scope atomic spin):
//   K1: wave per row. Ballots give every lane the full 256-col zero-mask in
//       4 ulls; each lane computes EXACT 1D nearest-zero distance for its 4
//       cols fully in registers, writes g as u16 row-major (coalesced).
//       Block 0 zeroes the 128-uint ctrl region (re-poison safe).
//   K2f: block = slice 16-col strip (768 blocks = 256 CU x 3, co-resident:
//       LDS 18.5 KB -> 8 blk/CU, waves_per_eu(3) -> VGPR<=170 -> 3 blk/CU).
//       g strip -> LDS (d^2 float, col-major stride 289, 16 pad rows/side);
//       own[16] rows in regs; +-16 paired window min-plus; EXACT fallback
//       (full-column rescan in LDS) when windowed min > 288 (|o|>=17
//       candidates >= 289). dmin stays in REGISTERS. Block max ->
//       atomicMax(ctrl[slice]) -> fence -> counter++ -> acquire-spin until
//       all 16 strips posted -> epilogue out = (mx - w*sqrt(d2))/mx written
//       straight from registers. d2 never touches HBM.
// Phase-2 work is uniform (~10 us) across blocks -> spin tail is small
// (unlike R1, whose 60 us imbalanced k2 made strips spin for tens of us).

#define PADV 1e30f

// ---------------- K1: register 1D EDT via ballots + ctrl zeroing ------------
// Lane l holds cols 4l..4l+3. b[cc] bit j = (col 4j+cc == 0).
// Left target for col p=4l+ci, residue cc: j <= l - (ci<cc); right: j >= l + (ci>cc).
__global__ __launch_bounds__(256) void k1_g16(const float* __restrict__ in,
                                              unsigned short* __restrict__ g,
                                              unsigned* __restrict__ ctrl) {
    if (blockIdx.x == 0 && threadIdx.x < 128) ctrl[threadIdx.x] = 0u;

    int row = blockIdx.x * 4 + (threadIdx.x >> 6);
    int lane = threadIdx.x & 63;
    const float4 m = ((const float4*)in)[(long)row * 64 + lane];

    unsigned long long b[4];
    b[0] = __ballot(m.x == 0.f);
    b[1] = __ballot(m.y == 0.f);
    b[2] = __ballot(m.z == 0.f);
    b[3] = __ballot(m.w == 0.f);

    unsigned long long loP = ~0ull >> (63 - lane);  // bits 0..lane
    unsigned long long loM = loP >> 1;              // bits 0..lane-1 (0 if lane==0)
    unsigned long long hiP = ~0ull << lane;         // bits lane..63
    unsigned long long hiM = hiP << 1;              // bits lane+1..63 (0 if lane==63)

    int LP[4], LM[4], RP[4], RM[4];
    #pragma unroll
    for (int cc = 0; cc < 4; ++cc) {
        unsigned long long mlp = b[cc] & loP;
        unsigned long long mlm = b[cc] & loM;
        unsigned long long mhp = b[cc] & hiP;
        unsigned long long mhm = b[cc] & hiM;
        LP[cc] = mlp ? 4 * (63 - __builtin_clzll(mlp)) + cc : -1000;  // nearest-left zero col
        LM[cc] = mlm ? 4 * (63 - __builtin_clzll(mlm)) + cc : -1000;
        RP[cc] = mhp ? 4 * __builtin_ctzll(mhp) + cc : 2000;          // nearest-right zero col
        RM[cc] = mhm ? 4 * __builtin_ctzll(mhm) + cc : 2000;
    }
    // colL(ci) = max( LP[cc] for cc<=ci, LM[cc] for cc>ci )
    int qp1 = max(LP[0], LP[1]);
    int qp2 = max(qp1, LP[2]);
    int qp3 = max(qp2, LP[3]);
    int sm3 = LM[3];
    int sm2 = max(LM[2], sm3);
    int sm1 = max(LM[1], sm2);
    int colL0 = max(LP[0], sm1);
    int colL1 = max(qp1, sm2);
    int colL2 = max(qp2, sm3);
    int colL3 = qp3;
    // colR(ci) = min( RM[cc] for cc<ci, RP[cc] for cc>=ci )
    int sp2 = min(RP[2], RP[3]);
    int sp1 = min(RP[1], sp2);
    int sp0 = min(RP[0], sp1);
    int pm0 = RM[0];
    int pm1 = min(pm0, RM[1]);
    int pm2 = min(pm1, RM[2]);
    int colR0 = sp0;
    int colR1 = min(pm0, sp1);
    int colR2 = min(pm1, sp2);
    int colR3 = min(pm2, RP[3]);

    int p0 = lane * 4;
    int d0 = min(min(p0 - colL0, colR0 - p0), 512);          // cap = BIG = H+W
    int d1 = min(min(p0 + 1 - colL1, colR1 - p0 - 1), 512);
    int d2 = min(min(p0 + 2 - colL2, colR2 - p0 - 2), 512);
    int d3 = min(min(p0 + 3 - colL3, colR3 - p0 - 3), 512);

    ushort4 v;
    v.x = (unsigned short)d0; v.y = (unsigned short)d1;
    v.z = (unsigned short)d2; v.w = (unsigned short)d3;
    ((ushort4*)(g + (long)row * 256))[lane] = v;             // coalesced 512 B/wave
}

// ---------------- K2f: column min-plus + fused epilogue ---------------------
// Block = 256 threads = one slice's 16-col strip (grid 48*16 = 768).
__global__ __launch_bounds__(256) __attribute__((amdgpu_waves_per_eu(3)))
void k2_fused(const unsigned short* __restrict__ g,
              float* __restrict__ out,
              unsigned* __restrict__ ctrl) {
    __shared__ float tile[16 * 289];   // 18496 B
    __shared__ float wm[4];
    __shared__ float sMx;
    int bx = blockIdx.x;
    int slice = bx >> 4;
    int w0 = (bx & 15) * 16;
    int tid = threadIdx.x;

    // fill tile: idx 0..287 <-> row idx-16 (u16 d -> float d^2 on the fly)
    #pragma unroll
    for (int pass = 0; pass < 2; ++pass) {
        int idx = pass * 256 + tid;
        if (pass == 0 || tid < 32) {
            int r = idx - 16;
            if (r >= 0 && r < 256) {
                const uint4* src = (const uint4*)(g + (long)slice * 65536 + (long)r * 256 + w0);
                #pragma unroll
                for (int j = 0; j < 2; ++j) {
                    uint4 q = src[j];
                    unsigned vv[4] = {q.x, q.y, q.z, q.w};
                    #pragma unroll
                    for (int e = 0; e < 4; ++e) {
                        float dl = (float)(vv[e] & 0xffffu);
                        float dh = (float)(vv[e] >> 16);
                        int col = j * 8 + e * 2;
                        tile[col * 289 + idx] = dl * dl;     // 2-way banking max
                        tile[(col + 1) * 289 + idx] = dh * dh;
                    }
                }
            } else {
                #pragma unroll
                for (int cc = 0; cc < 16; ++cc) tile[cc * 289 + idx] = PADV;
            }
        }
    }
    __syncthreads();

    int c = tid & 15;                  // column within strip
    int rg = tid >> 4;                 // 0..15
    int r0 = rg * 16;                  // owned rows r0..r0+15
    int i0 = 16 + r0;                  // tile index of first owned row

    float own[16], lo[16], hi[16];
    #pragma unroll
    for (int k = 0; k < 16; ++k) own[k] = tile[c * 289 + i0 + k];
    #pragma unroll
    for (int i = 0; i < 16; ++i) {
        lo[i] = tile[c * 289 + i0 - 16 + i];   // rows r0-16..r0-1 (pads rg==0)
        hi[i] = tile[c * 289 + i0 + 16 + i];   // rows r0+16..r0+31 (pads rg==15)
    }

    // window min-plus, +-o paired: min(s[k-o], s[k+o]) + o^2
    float dmin[16];
    #pragma unroll
    for (int k = 0; k < 16; ++k) dmin[k] = own[k];
    #pragma unroll
    for (int o = 1; o <= 16; ++o) {
        float oo = (float)(o * o);
        #pragma unroll
        for (int k = 0; k < 16; ++k) {
            int jm = k - o, jp = k + o;
            float a = (jm >= 0) ? own[jm] : lo[jm + 16];
            float b = (jp < 16) ? own[jp] : hi[jp - 16];
            dmin[k] = fminf(dmin[k], fminf(a, b) + oo);
        }
    }

    // exact fallback: windowed min > 288 can't certify +-16 optimality;
    // rescan the full column (in LDS). Never taken for random masks (execz).
    #pragma unroll
    for (int k = 0; k < 16; ++k) {
        if (dmin[k] > 288.0f) {
            float best = dmin[k];
            int r = r0 + k;
            for (int rp = 0; rp < 256; ++rp) {
                float dr = (float)(r - rp);
                best = fminf(best, fmaf(dr, dr, tile[c * 289 + 16 + rp]));
            }
            dmin[k] = best;
        }
    }

    // block max -> slice max via device-scope atomics; spin until 16 strips
    float mmax = 0.f;
    #pragma unroll
    for (int k = 0; k < 16; ++k) mmax = fmaxf(mmax, dmin[k]);
    #pragma unroll
    for (int off = 32; off >= 1; off >>= 1)
        mmax = fmaxf(mmax, __shfl_down(mmax, off, 64));
    if ((tid & 63) == 0) wm[tid >> 6] = mmax;
    __syncthreads();
    if (tid == 0) {
        float bmax = fmaxf(fmaxf(wm[0], wm[1]), fmaxf(wm[2], wm[3]));
        atomicMax(ctrl + slice, __float_as_uint(bmax));   // float-as-uint: d2>=0
        __threadfence();                                  // publish before count
        atomicAdd(ctrl + 64 + slice, 1u);
        while (__hip_atomic_load(ctrl + 64 + slice, __ATOMIC_ACQUIRE,
                                 __HIP_MEMORY_SCOPE_AGENT) < 16u) {
            __builtin_amdgcn_s_sleep(2);
        }
        sMx = __uint_as_float(__hip_atomic_load(ctrl + slice, __ATOMIC_RELAXED,
                                                __HIP_MEMORY_SCOPE_AGENT));
    }
    __syncthreads();

    // fused epilogue: out = (mx - w*sqrt(d2)) / mx straight from registers
    int ch = slice % 3;
    float wgt = (ch == 0) ? 0.5f : ((ch == 1) ? 1.0f : 2.0f);
    float mx = wgt * __builtin_sqrtf(sMx);
    float* dst = out + (long)slice * 65536 + w0 + c;
    if (mx > 0.f) {
        float inv = 1.0f / mx;
        #pragma unroll
        for (int k = 0; k < 16; ++k)
            dst[(long)(r0 + k) * 256] = (mx - wgt * __builtin_sqrtf(dmin[k])) * inv;
    } else {
        #pragma unroll
        for (int k = 0; k < 16; ++k)
            dst[(long)(r0 + k) * 256] = wgt * __builtin_sqrtf(dmin[k]);
    }
}

extern "C" void kernel_launch(void* const* d_in, const int* in_sizes, int n_in,
                              void* d_out, int out_size, void* d_ws, size_t ws_size,
                              hipStream_t stream) {
    const float* in = (const float*)d_in[0];
    float* out = (float*)d_out;
    unsigned* ctrl = (unsigned*)d_ws;                                  // 128 uints
    unsigned short* g = (unsigned short*)((char*)d_ws + 4096);         // 6.29 MB

    k1_g16<<<3072, 256, 0, stream>>>(in, g, ctrl);        // 12288 rows, wave/row
    k2_fused<<<768, 256, 0, stream>>>(g, out, ctrl);      // strips + fused epilogue
}